// Round 10
// baseline (251.484 us; speedup 1.0000x reference)
//
#include <hip/hip_runtime.h>
#include <math.h>

#define N_NODES 40000
#define N_EDGES 640000
#define HIDDEN 128
#define N_LAYERS 4
#define N_CLASSES 40
#define SCALING 0.08838834764831845f

typedef __attribute__((ext_vector_type(8))) short short8;
typedef __attribute__((ext_vector_type(4))) float floatx4;

static __device__ __forceinline__ float b2f(unsigned short u) {
  return __uint_as_float(((unsigned)u) << 16);
}
static __device__ __forceinline__ unsigned short f2b(float f) {
  unsigned u = __float_as_uint(f);
  u += 0x7fff + ((u >> 16) & 1);   // round-to-nearest-even
  return (unsigned short)(u >> 16);
}

// ---------------- setup: cast h0 -> bf16 g0, build CSR -------------------------
__global__ __launch_bounds__(256) void setup_all(
    const float* __restrict__ h_in, const int* __restrict__ dst,
    unsigned short* __restrict__ g0, int* __restrict__ row_start)
{
  int idx = blockIdx.x * 256 + threadIdx.x;
  if (idx < 640000) {                 // 40000*128/8 vector casts
    const float4* p = (const float4*)h_in + (size_t)idx * 2;
    float4 a = p[0], b = p[1];
    union { unsigned short us[8]; uint4 v; } o;
    o.us[0] = f2b(a.x); o.us[1] = f2b(a.y); o.us[2] = f2b(a.z); o.us[3] = f2b(a.w);
    o.us[4] = f2b(b.x); o.us[5] = f2b(b.y); o.us[6] = f2b(b.z); o.us[7] = f2b(b.w);
    ((uint4*)g0)[idx] = o.v;
    return;
  }
  int c = idx - 640000;
  if (c <= N_NODES) {                 // row_start[c] = lower_bound(dst, c)
    int lo = 0, hi = N_EDGES;
    while (lo < hi) {
      int mid = (lo + hi) >> 1;
      if (dst[mid] < c) lo = mid + 1; else hi = mid;
    }
    row_start[c] = lo;
  }
}

// ---------------- batched f32 128x128 products (weight folding) ----------------
// AB form:  out[r][c] = sum_j A[r][j] * B[j*ncolsB + c]
// ABt form: out[r][c] = sum_j A[r][j] * B[c*128 + j]
// storeT: write out[c][r] (row stride 128), zero-padding rows [ncolsB, padrows).
struct MMJob {
  const float* A; const float* B;
  float* Cf; unsigned short* Cb;
  float scale;
  int abt; int ncolsB; int storeT; int padrows;
};
struct MMStage { MMJob jobs[4]; int njobs; int bias; };

__global__ __launch_bounds__(256) void mm_stage(
    MMStage st,
    const float* __restrict__ Wq, const float* __restrict__ Wk,
    const float* __restrict__ Wv, const float* __restrict__ Wout,
    const float* __restrict__ bq, const float* __restrict__ bv,
    const float* __restrict__ bout,
    const float* __restrict__ C2, const float* __restrict__ C3,
    float* __restrict__ zb, float* __restrict__ bout2)
{
  int blk = blockIdx.x;
  if (blk < st.njobs * 64) {
    MMJob J = st.jobs[blk >> 6];
    int bi = blk & 63;
    int ty = threadIdx.x >> 7;        // 0..1
    int c  = threadIdx.x & 127;
    int r  = bi * 2 + ty;
    float acc = 0.f;
    if (J.abt) {
      const float* ar = J.A + (size_t)r * 128;
      const float* br = J.B + (size_t)c * 128;
      #pragma unroll 4
      for (int j = 0; j < 128; ++j) acc += ar[j] * br[j];
    } else if (c < J.ncolsB) {
      const float* ar = J.A + (size_t)r * 128;
      #pragma unroll 4
      for (int j = 0; j < 128; ++j) acc += ar[j] * J.B[(size_t)j * J.ncolsB + c];
    }
    acc *= J.scale;
    if (J.storeT) {
      if (c < J.ncolsB) {
        if (J.Cb) J.Cb[(size_t)c * 128 + r] = f2b(acc);
        else      J.Cf[(size_t)c * 128 + r] = acc;
      } else if (c < J.padrows && J.Cb) {
        J.Cb[(size_t)c * 128 + r] = 0;
      }
    } else if (c < J.ncolsB) {
      if (J.Cb) J.Cb[(size_t)r * J.ncolsB + c] = f2b(acc);
      else      J.Cf[(size_t)r * J.ncolsB + c] = acc;
    }
    return;
  }
  if (!st.bias) return;

  // ---- bias block (zeros in this dataset, kept for exactness) ----
  int t = threadIdx.x;
  __shared__ float cb[128], v1[128], v2[128], cbn[128];
  if (t < 128) {
    const float* wk0 = Wk + (size_t)t * 128;
    float s = 0.f;
    for (int o = 0; o < 128; ++o) s += bq[o] * wk0[o];
    zb[t] = s * SCALING;              // zb layer 0 (Cv = I)
    cb[t] = bv[t];                    // cb^{(1)} = bv_0
  }
  __syncthreads();
  for (int l = 1; l < 4; ++l) {
    const float* Cvl = (l == 1) ? Wv : (l == 2 ? C2 : C3);
    if (t < 128) {
      float s = bq[(size_t)l * 128 + t];
      for (int o = 0; o < 128; ++o) s += cb[o] * Wq[(size_t)l * 16384 + (size_t)o * 128 + t];
      v1[t] = s;
    }
    __syncthreads();
    if (t < 128) {
      float s = 0.f;
      const float* wkr = Wk + (size_t)l * 16384 + (size_t)t * 128;
      for (int o = 0; o < 128; ++o) s += v1[o] * wkr[o];
      v2[t] = s;
    }
    __syncthreads();
    if (t < 128) {
      float s = 0.f;
      const float* cvr = Cvl + (size_t)t * 128;
      for (int d = 0; d < 128; ++d) s += v2[d] * cvr[d];
      zb[(size_t)l * 128 + t] = s * SCALING;
      float s2 = bv[(size_t)l * 128 + t];
      for (int d = 0; d < 128; ++d) s2 += cb[d] * Wv[(size_t)l * 16384 + (size_t)d * 128 + t];
      cbn[t] = s2;
    }
    __syncthreads();
    if (t < 128) cb[t] = cbn[t];
    __syncthreads();
  }
  if (t < N_CLASSES) {
    float s = bout[t];
    for (int d = 0; d < 128; ++d) s += cb[d] * Wout[(size_t)d * N_CLASSES + t];
    bout2[t] = s;
  }
}

// ---------------- node GEMM via MFMA bf16, LDS-staged coalesced epilogue -------
// z[node][128] = g[node][:] @ WZ^T + zb. 16 rows x 64 cols per wave; grid 1250.
__global__ __launch_bounds__(256) void gemm_z(
    const unsigned short* __restrict__ A,     // 40000x128 bf16
    const unsigned short* __restrict__ Wt,    // [128][128] bf16, out-major
    const float* __restrict__ bias,           // [128] f32
    unsigned short* __restrict__ C)           // 40000x128 bf16
{
  constexpr int ROWB = 256;                   // bytes per output row
  __shared__ __align__(16) unsigned char cs[32 * ROWB];

  const int tid = threadIdx.x;
  const int wid = tid >> 6, lane = tid & 63;
  const int r = lane & 15, kg = lane >> 4;
  const int colhalf = wid & 1, rowsub = wid >> 1;
  const int colbase = colhalf * 64;
  const int ro = rowsub * 16 + r;             // local row 0..31
  const int row = blockIdx.x * 32 + ro;       // always < 40000

  short8 hf[4];
  #pragma unroll
  for (int kc = 0; kc < 4; ++kc)
    hf[kc] = *(const short8*)(A + (size_t)row * 128 + kc * 32 + kg * 8);

  floatx4 acc[4];
  #pragma unroll
  for (int df = 0; df < 4; ++df) acc[df] = (floatx4){0.f, 0.f, 0.f, 0.f};

  const unsigned short* wp = Wt + (size_t)(colbase + r) * 128 + kg * 8;
  #pragma unroll
  for (int df = 0; df < 4; ++df) {
    #pragma unroll
    for (int kc = 0; kc < 4; ++kc) {
      short8 wf = *(const short8*)(wp + df * 2048 + kc * 32);
      acc[df] = __builtin_amdgcn_mfma_f32_16x16x32_bf16(wf, hf[kc], acc[df], 0, 0, 0);
    }
  }

  #pragma unroll
  for (int df = 0; df < 4; ++df) {
    float4 b4 = *(const float4*)&bias[colbase + df * 16 + kg * 4];
    union { unsigned short us[4]; uint2 u2; } o;
    o.us[0] = f2b(acc[df][0] + b4.x);
    o.us[1] = f2b(acc[df][1] + b4.y);
    o.us[2] = f2b(acc[df][2] + b4.z);
    o.us[3] = f2b(acc[df][3] + b4.w);
    int colb = (colbase + df * 16 + kg * 4) * 2;
    *(uint2*)(cs + ro * ROWB + (colb ^ ((ro & 7) << 4))) = o.u2;
  }
  __syncthreads();

  unsigned char* dstb = (unsigned char*)(C + (size_t)blockIdx.x * 32 * 128);
  #pragma unroll
  for (int i = 0; i < 2; ++i) {
    int byte = (i * 256 + tid) * 16;
    int ro2 = byte / ROWB;
    int colb2 = byte & (ROWB - 1);
    *(uint4*)(dstb + byte) =
        *(const uint4*)(cs + ro2 * ROWB + (colb2 ^ ((ro2 & 7) << 4)));
  }
}

// ---------------- fused edge attention: score + softmax + g-aggregate ----------
// score_e = z[dst] . g[src]; gout[i] = sum_e softmax(score) * g[src_e].
__global__ __launch_bounds__(128) void edge_fused(
    const unsigned short* __restrict__ z, const unsigned short* __restrict__ g,
    const int* __restrict__ src, const int* __restrict__ row_start,
    unsigned short* __restrict__ gout)
{
  const int lane = threadIdx.x & 63;
  const int node = blockIdx.x * 2 + (threadIdx.x >> 6);   // 40000 % 2 == 0
  const int sg = lane >> 4, sl = lane & 15;

  short8 qf = *(const short8*)(z + ((size_t)node << 7) + sl * 8);
  float qd[8];
  #pragma unroll
  for (int j = 0; j < 8; ++j) qd[j] = b2f((unsigned short)qf[j]);

  const int r0 = row_start[node], r1 = row_start[node + 1];

  float acc[8] = {0.f, 0.f, 0.f, 0.f, 0.f, 0.f, 0.f, 0.f};
  float ws = 0.f;

#define LOADG(VLD, HF, C)                                               \
  {                                                                     \
    int e_ = (C) + sg;                                                  \
    VLD = e_ < r1;                                                      \
    int s_ = VLD ? src[e_] : 0;                                         \
    HF = *(const short8*)(g + ((size_t)s_ << 7) + sl * 8);              \
  }

#define COMPG(VLD, HF)                                                  \
  {                                                                     \
    float hd_[8];                                                       \
    _Pragma("unroll")                                                   \
    for (int j = 0; j < 8; ++j) hd_[j] = b2f((unsigned short)HF[j]);    \
    float d0_ = 0.f, d1_ = 0.f;                                         \
    _Pragma("unroll")                                                   \
    for (int j = 0; j < 4; ++j) d0_ += qd[j] * hd_[j];                  \
    _Pragma("unroll")                                                   \
    for (int j = 4; j < 8; ++j) d1_ += qd[j] * hd_[j];                  \
    float d_ = d0_ + d1_;                                               \
    d_ += __shfl_xor(d_, 1, 64);                                        \
    d_ += __shfl_xor(d_, 2, 64);                                        \
    d_ += __shfl_xor(d_, 4, 64);                                        \
    d_ += __shfl_xor(d_, 8, 64);                                        \
    float w_ = VLD ? __expf(d_) : 0.f;                                  \
    ws += w_;                                                           \
    _Pragma("unroll")                                                   \
    for (int j = 0; j < 8; ++j) acc[j] += w_ * hd_[j];                  \
  }

  bool vA, vB;
  short8 hA, hB;
  LOADG(vA, hA, r0);
  LOADG(vB, hB, r0 + 4);

  for (int c = r0; c < r1; c += 8) {
    bool vC, vD;
    short8 hC, hD;
    LOADG(vC, hC, c + 8);
    LOADG(vD, hD, c + 12);
    COMPG(vA, hA);
    COMPG(vB, hB);
    vA = vC; hA = hC;
    vB = vD; hB = hD;
  }

#undef LOADG
#undef COMPG

  #pragma unroll
  for (int off = 16; off <= 32; off <<= 1) {
    ws += __shfl_xor(ws, off, 64);
    #pragma unroll
    for (int j = 0; j < 8; ++j) acc[j] += __shfl_xor(acc[j], off, 64);
  }

  if (sg == 0) {
    float inv = (ws > 1e-20f) ? 1.0f / ws : 0.0f;
    union { unsigned short us[8]; uint4 u4; } o;
    #pragma unroll
    for (int j = 0; j < 8; ++j) o.us[j] = f2b(acc[j] * inv);
    *(uint4*)(gout + (size_t)node * 128 + sl * 8) = o.u4;
  }
}

// ---------------- output head via MFMA: logits + log_softmax -------------------
// grid 625, 16 rows/wave; LDS-staged contiguous f32 stores.
__global__ __launch_bounds__(256) void out_head_mfma(
    const unsigned short* __restrict__ h, const unsigned short* __restrict__ wout_t,
    const float* __restrict__ bout, float* __restrict__ out)
{
  __shared__ __align__(16) float os[64 * N_CLASSES];   // 10240 B

  const int wid = threadIdx.x >> 6, lane = threadIdx.x & 63;
  const int r = lane & 15, kg = lane >> 4;
  const int row_base = blockIdx.x * 64 + wid * 16;
  const int ar = row_base + r;

  floatx4 acc[3];
  #pragma unroll
  for (int n = 0; n < 3; ++n) acc[n] = (floatx4){0.f, 0.f, 0.f, 0.f};

  const unsigned short* ap = h + (size_t)ar * 128 + kg * 8;
  const unsigned short* bp = wout_t + (size_t)r * 128 + kg * 8;

  #pragma unroll
  for (int kc = 0; kc < 128; kc += 32) {
    short8 a0 = *(const short8*)(ap + kc);
    #pragma unroll
    for (int n = 0; n < 3; ++n) {
      short8 b = *(const short8*)(bp + n * 2048 + kc);
      acc[n] = __builtin_amdgcn_mfma_f32_16x16x32_bf16(a0, b, acc[n], 0, 0, 0);
    }
  }

  float bn0 = bout[r];
  float bn1 = bout[16 + r];
  float bn2 = (r < 8) ? bout[32 + r] : 0.f;

  #pragma unroll
  for (int g = 0; g < 4; ++g) {
    int rl = wid * 16 + kg * 4 + g;          // local row 0..63
    float l0 = acc[0][g] + bn0;
    float l1 = acc[1][g] + bn1;
    float l2 = acc[2][g] + bn2;              // valid only if r < 8
    float m = fmaxf(l0, l1);
    if (r < 8) m = fmaxf(m, l2);
    #pragma unroll
    for (int off = 8; off >= 1; off >>= 1) m = fmaxf(m, __shfl_xor(m, off, 64));
    float s = __expf(l0 - m) + __expf(l1 - m) + ((r < 8) ? __expf(l2 - m) : 0.f);
    #pragma unroll
    for (int off = 8; off >= 1; off >>= 1) s += __shfl_xor(s, off, 64);
    float lse = m + logf(s);
    os[rl * N_CLASSES + r]      = l0 - lse;
    os[rl * N_CLASSES + 16 + r] = l1 - lse;
    if (r < 8) os[rl * N_CLASSES + 32 + r] = l2 - lse;
  }
  __syncthreads();

  float* dstb = out + (size_t)blockIdx.x * 64 * N_CLASSES;
  #pragma unroll
  for (int i = 0; i < 3; ++i) {
    int idx = i * 256 + threadIdx.x;
    if (idx < 640)
      *(uint4*)(dstb + idx * 4) = *(const uint4*)(os + idx * 4);
  }
}

extern "C" void kernel_launch(void* const* d_in, const int* in_sizes, int n_in,
                              void* d_out, int out_size, void* d_ws, size_t ws_size,
                              hipStream_t stream) {
  const float* h_in = (const float*)d_in[0];
  const int*   src  = (const int*)d_in[1];
  const int*   dst  = (const int*)d_in[2];
  const float* Wq   = (const float*)d_in[3];
  const float* bq   = (const float*)d_in[4];
  const float* Wk   = (const float*)d_in[5];
  const float* bk   = (const float*)d_in[6];  // cancels in softmax (dst-constant)
  const float* Wv   = (const float*)d_in[7];
  const float* bv   = (const float*)d_in[8];
  const float* Wout = (const float*)d_in[9];
  const float* bout = (const float*)d_in[10];
  float* out = (float*)d_out;
  (void)bk;

  char* ws = (char*)d_ws;
  size_t off = 0;
  auto alloc = [&](size_t bytes) -> void* {
    void* p = ws + off;
    off += (bytes + 255) & ~(size_t)255;
    return p;
  };
  int*            row_start = (int*)           alloc((size_t)(N_NODES + 1) * sizeof(int));
  unsigned short* g0        = (unsigned short*)alloc((size_t)N_NODES * 128 * 2);
  unsigned short* g1        = (unsigned short*)alloc((size_t)N_NODES * 128 * 2);
  unsigned short* zbuf      = (unsigned short*)alloc((size_t)N_NODES * 128 * 2);
  unsigned short* WZ        = (unsigned short*)alloc((size_t)4 * 16384 * 2);
  unsigned short* WOt       = (unsigned short*)alloc((size_t)48 * 128 * 2);
  float*          C2        = (float*)alloc(16384 * sizeof(float));
  float*          C3        = (float*)alloc(16384 * sizeof(float));
  float*          C4        = (float*)alloc(16384 * sizeof(float));
  float*          Abuf      = (float*)alloc(3 * 16384 * sizeof(float));
  float*          Bbuf      = (float*)alloc(3 * 16384 * sizeof(float));
  float*          zb        = (float*)alloc(4 * 128 * sizeof(float));
  float*          bout2     = (float*)alloc(64 * sizeof(float));

  setup_all<<<(680001 + 255) / 256, 256, 0, stream>>>(h_in, dst, g0, row_start);

  auto J = [](const float* A, const float* B, float* Cf, unsigned short* Cb,
              float scale, int abt, int ncolsB, int storeT, int padrows) {
    MMJob j; j.A = A; j.B = B; j.Cf = Cf; j.Cb = Cb; j.scale = scale;
    j.abt = abt; j.ncolsB = ncolsB; j.storeT = storeT; j.padrows = padrows;
    return j;
  };
  const float* Wq_l[4] = {Wq, Wq + 16384, Wq + 32768, Wq + 49152};
  const float* Wk_l[4] = {Wk, Wk + 16384, Wk + 32768, Wk + 49152};
  const float* Wv_l[4] = {Wv, Wv + 16384, Wv + 32768, Wv + 49152};

  MMStage s0 = {};
  s0.jobs[0] = J(Wk_l[0], Wq_l[0], nullptr, WZ, SCALING, 1, 128, 0, 0);
  s0.jobs[1] = J(Wv_l[0], Wv_l[1], C2, nullptr, 1.f, 0, 128, 0, 0);
  s0.jobs[2] = J(Wv_l[0], Wk_l[1], Abuf, nullptr, 1.f, 0, 128, 0, 0);
  s0.jobs[3] = J(Wv_l[0], Wq_l[1], Bbuf, nullptr, 1.f, 0, 128, 0, 0);
  s0.njobs = 4; s0.bias = 0;

  MMStage s1 = {};
  s1.jobs[0] = J(Abuf, Bbuf, nullptr, WZ + 16384, SCALING, 1, 128, 0, 0);
  s1.jobs[1] = J(C2, Wv_l[2], C3, nullptr, 1.f, 0, 128, 0, 0);
  s1.jobs[2] = J(C2, Wk_l[2], Abuf + 16384, nullptr, 1.f, 0, 128, 0, 0);
  s1.jobs[3] = J(C2, Wq_l[2], Bbuf + 16384, nullptr, 1.f, 0, 128, 0, 0);
  s1.njobs = 4; s1.bias = 0;

  MMStage s2 = {};
  s2.jobs[0] = J(Abuf + 16384, Bbuf + 16384, nullptr, WZ + 32768, SCALING, 1, 128, 0, 0);
  s2.jobs[1] = J(C3, Wv_l[3], C4, nullptr, 1.f, 0, 128, 0, 0);
  s2.jobs[2] = J(C3, Wk_l[3], Abuf + 32768, nullptr, 1.f, 0, 128, 0, 0);
  s2.jobs[3] = J(C3, Wq_l[3], Bbuf + 32768, nullptr, 1.f, 0, 128, 0, 0);
  s2.njobs = 4; s2.bias = 0;

  MMStage s3 = {};
  s3.jobs[0] = J(Abuf + 32768, Bbuf + 32768, nullptr, WZ + 49152, SCALING, 1, 128, 0, 0);
  s3.jobs[1] = J(C4, Wout, nullptr, WOt, 1.f, 0, N_CLASSES, 1, 48);
  s3.njobs = 2; s3.bias = 1;

  mm_stage<<<4 * 64, 256, 0, stream>>>(s0, Wq, Wk, Wv, Wout, bq, bv, bout, C2, C3, zb, bout2);
  mm_stage<<<4 * 64, 256, 0, stream>>>(s1, Wq, Wk, Wv, Wout, bq, bv, bout, C2, C3, zb, bout2);
  mm_stage<<<4 * 64, 256, 0, stream>>>(s2, Wq, Wk, Wv, Wout, bq, bv, bout, C2, C3, zb, bout2);
  mm_stage<<<2 * 64 + 1, 256, 0, stream>>>(s3, Wq, Wk, Wv, Wout, bq, bv, bout, C2, C3, zb, bout2);

  unsigned short* gcur = g0;
  unsigned short* gnext = g1;
  for (int l = 0; l < N_LAYERS; ++l) {
    gemm_z<<<1250, 256, 0, stream>>>(gcur, WZ + (size_t)l * 16384, zb + (size_t)l * 128, zbuf);
    edge_fused<<<N_NODES / 2, 128, 0, stream>>>(zbuf, gcur, src, row_start, gnext);
    unsigned short* tmp = gcur; gcur = gnext; gnext = tmp;
  }
  out_head_mfma<<<625, 256, 0, stream>>>(gcur, WOt, bout2, out);
}